// Round 2
// baseline (149.307 us; speedup 1.0000x reference)
//
#include <hip/hip_runtime.h>
#include <math.h>

// OnlineTripletLoss on MI355X — Round 12 (= R11 resubmit; R11 bench was an
// infrastructure failure: "container failed twice", no kernel verdict).
// R10 evidence: fused = 85us but total = 142us -> ~57us in prep + launch overhead.
//   prep ran 128 blocks on 256 CUs (half the GPU idle). MfmaUtil 26% vs 21us MFMA
//   floor: per-kk __syncthreads() emits vmcnt(0) full-drain (2-phase ceiling).
// Changes vs R10:
//  (1) prep: 8 rows/block -> 512 blocks (2/CU), same pan layout, LDS row-sum reduce.
//  (2) fused K-loop: triple-buffered staging (72 KB, still 2 blocks/CU), prefetch
//      2 iterations ahead, counted s_waitcnt vmcnt(3) + raw s_barrier (never drain
//      to 0 in-loop), s_setprio(1) around the 12-MFMA cluster (T3/T4/T5).
// ws: sq[N] | hp[N] | hn_fall[N] | hn_semi[N] | bars[1024] | pad | pan[N*2D] f16

constexpr float MARGIN = 0.3f;

typedef _Float16 half8    __attribute__((ext_vector_type(8)));
typedef float    floatx16 __attribute__((ext_vector_type(16)));

#define GLD_LDS16(gp, lp)                                                              \
    __builtin_amdgcn_global_load_lds(                                                  \
        (const __attribute__((address_space(1))) void*)(gp),                           \
        (__attribute__((address_space(3))) void*)(lp), 16, 0, 0)

// prep: 8 rows/block (512 blocks); builds pan[p][kc][r][8] (kc<64 hi, kc>=64 lo),
// sq, per-row init, bars. Writes: 8-row x 16B = 128B contiguous clusters.
__global__ __launch_bounds__(256)
void prep_kernel(const float* __restrict__ e, _Float16* __restrict__ pan,
                 float* __restrict__ sq, unsigned int* __restrict__ hp,
                 unsigned int* __restrict__ hn_fall, unsigned int* __restrict__ hn_semi,
                 unsigned int* __restrict__ bars, int N, int D) {
    __shared__ float red[256];
    if (blockIdx.x == 0 && threadIdx.x < 32) bars[threadIdx.x * 32] = 0u;
    const int r0  = blockIdx.x * 8;
    const int p   = r0 >> 7;
    const int rl  = r0 & 127;
    const int r   = threadIdx.x & 7;      // row within block (inner -> coalesced writes)
    const int c8  = threadIdx.x >> 3;     // k-chunk group 0..31
    const int row = r0 + r;
    const float* er = e + (size_t)row * D;
    float s = 0.f;
    #pragma unroll
    for (int it = 0; it < 2; ++it) {
        const int kw = c8 + it * 32;      // 0..63
        const float4 x0 = *(const float4*)&er[kw * 8];
        const float4 x1 = *(const float4*)&er[kw * 8 + 4];
        const float xv[8] = {x0.x, x0.y, x0.z, x0.w, x1.x, x1.y, x1.z, x1.w};
        half8 hi, lo;
        #pragma unroll
        for (int j = 0; j < 8; ++j) {
            _Float16 h = (_Float16)xv[j];
            hi[j] = h;
            lo[j] = (_Float16)(xv[j] - (float)h);
            s += xv[j] * xv[j];
        }
        *(half8*)&pan[((size_t)(p * 128 + kw) * 128 + rl + r) * 8]      = hi;
        *(half8*)&pan[((size_t)(p * 128 + 64 + kw) * 128 + rl + r) * 8] = lo;
    }
    red[threadIdx.x] = s;
    __syncthreads();
    if (threadIdx.x < 8) {
        float t = 0.f;
        #pragma unroll
        for (int c = 0; c < 32; ++c) t += red[threadIdx.x + 8 * c];
        const int rw = r0 + threadIdx.x;
        sq[rw]      = t;
        hp[rw]      = 0u;           // max identity (dist >= 0)
        hn_fall[rw] = 0u;
        hn_semi[rw] = 0x7f800000u;  // +inf (min identity)
    }
}

// Fused kernel: tile 256(rows) x 128(cols), 512 thr = 8 waves (4x2) of 64x64.
// Triple-buffered DMA staging (BK=16, prefetch depth 2, counted vmcnt),
// swapped-operand MFMA, per-row-panel barrier, last-block final reduction.
__global__ __launch_bounds__(512, 4)
void fused_kernel(const _Float16* __restrict__ pan, const int* __restrict__ labels,
                  const float* __restrict__ sq,
                  unsigned int* __restrict__ hp,
                  unsigned int* __restrict__ hn_fall,
                  unsigned int* __restrict__ hn_semi,
                  unsigned int* __restrict__ bars,
                  float* __restrict__ out,
                  int N, int D, unsigned int nrowblocks, unsigned int nblocks) {
    // per buffer (12288 halves = 24 KB): A[kcl(4)][r(256)][8] | B[kcl(4)][r(128)][8]
    // kcl: 0,1 = hi k-chunks (2kk, 2kk+1); 2,3 = lo k-chunks.
    __shared__ __attribute__((aligned(16))) _Float16 S[3][12288];   // 72 KB
    __shared__ float sq_r[256], sq_c[128], hp_r[256];
    __shared__ int   lab_r[256], lab_c[128];
    __shared__ int   lastflag;

    const int tid  = threadIdx.x;
    const int lane = tid & 63;
    const int wave = tid >> 6;            // 0..7
    const int wr = (wave >> 1) * 64;      // 0,64,128,192
    const int wc = (wave & 1) * 64;       // 0,64
    const int mrow = lane & 31;
    const int half_id = lane >> 5;

    // XCD swizzle: 8 regions of 8(px) x 8(py) over the 32 x 16 tile grid
    const int j  = blockIdx.x & 7;
    const int i  = blockIdx.x >> 3;       // 0..63
    const int px = (j & 3) * 8 + (i & 7);         // 0..31 (128-col tiles)
    const int py = (j >> 2) * 8 + (i >> 3);       // 0..15 (256-row tiles)
    const int rowBase = py * 256;
    const int colBase = px * 128;

    if (tid < 256) {
        sq_r[tid]  = sq[rowBase + tid];
        lab_r[tid] = labels[rowBase + tid];
    } else if (tid < 384) {
        const int t = tid - 256;
        sq_c[t]  = sq[colBase + t];
        lab_c[t] = labels[colBase + t];
    }

    floatx16 acc[2][2];   // acc[bj][ai]: cols in regs (bj), rows in lanes (ai)
    #pragma unroll
    for (int a = 0; a < 2; ++a)
        #pragma unroll
        for (int b = 0; b < 2; ++b)
            #pragma unroll
            for (int r = 0; r < 16; ++r) acc[a][b][r] = 0.f;

    // staging: 24 slabs of 1KB per stage (A 16, B 8); wave w issues slabs 3w..3w+2
    auto stage = [&](int bufid, int kkv) {
        #pragma unroll
        for (int t = 0; t < 3; ++t) {
            const int s = wave * 3 + t;
            int kcl, p, row0, lofs;
            if (s < 16) {            // A slab: kcl = s>>2, row-quarter rq = s&3
                const int rq = s & 3;
                kcl  = s >> 2;
                p    = 2 * py + (rq >> 1);
                row0 = (rq & 1) * 64;
                lofs = (kcl * 256 + rq * 64) * 8;
            } else {                 // B slab
                const int u = s - 16;
                kcl  = u >> 1;
                p    = px;
                row0 = (u & 1) * 64;
                lofs = 8192 + (kcl * 128 + row0) * 8;
            }
            const int kc = (kcl < 2) ? (2 * kkv + kcl) : (64 + 2 * kkv + (kcl - 2));
            const _Float16* g = pan + ((size_t)(p * 128 + kc) * 128 + row0 + lane) * 8;
            GLD_LDS16(g, &S[bufid][lofs]);
        }
    };

    // prologue: prefetch kk=0 and kk=1; wait only for kk=0's 3 slabs (oldest).
    stage(0, 0);
    stage(1, 1);
    asm volatile("s_waitcnt vmcnt(3)" ::: "memory");
    __builtin_amdgcn_s_barrier();
    asm volatile("" ::: "memory");

    int b = 0;
    #pragma unroll 1
    for (int kk = 0; kk < 32; ++kk) {
        // S[b] is ready for all waves here.
        const int rA = wr + mrow, cB = wc + mrow;
        const _Float16* Sb = &S[b][0];
        const half8 ah0 = *(const half8*)&Sb[(half_id * 256 + rA) * 8];
        const half8 ah1 = *(const half8*)&Sb[(half_id * 256 + rA + 32) * 8];
        const half8 al0 = *(const half8*)&Sb[((2 + half_id) * 256 + rA) * 8];
        const half8 al1 = *(const half8*)&Sb[((2 + half_id) * 256 + rA + 32) * 8];
        const half8 bh0 = *(const half8*)&Sb[8192 + (half_id * 128 + cB) * 8];
        const half8 bh1 = *(const half8*)&Sb[8192 + (half_id * 128 + cB + 32) * 8];
        const half8 bl0 = *(const half8*)&Sb[8192 + ((2 + half_id) * 128 + cB) * 8];
        const half8 bl1 = *(const half8*)&Sb[8192 + ((2 + half_id) * 128 + cB + 32) * 8];
        // prefetch kk+2 into the buffer last read at kk-1 (reads done pre-barrier).
        int sb = b + 2; if (sb >= 3) sb -= 3;
        if (kk + 2 < 32) stage(sb, kk + 2);
        // swapped operands: D[col(reg)][row(lane)] ; dot = hi.hi + lo.hi + hi.lo
        __builtin_amdgcn_s_setprio(1);
        acc[0][0] = __builtin_amdgcn_mfma_f32_32x32x16_f16(bh0, ah0, acc[0][0], 0, 0, 0);
        acc[0][1] = __builtin_amdgcn_mfma_f32_32x32x16_f16(bh0, ah1, acc[0][1], 0, 0, 0);
        acc[1][0] = __builtin_amdgcn_mfma_f32_32x32x16_f16(bh1, ah0, acc[1][0], 0, 0, 0);
        acc[1][1] = __builtin_amdgcn_mfma_f32_32x32x16_f16(bh1, ah1, acc[1][1], 0, 0, 0);
        acc[0][0] = __builtin_amdgcn_mfma_f32_32x32x16_f16(bl0, ah0, acc[0][0], 0, 0, 0);
        acc[0][1] = __builtin_amdgcn_mfma_f32_32x32x16_f16(bl0, ah1, acc[0][1], 0, 0, 0);
        acc[1][0] = __builtin_amdgcn_mfma_f32_32x32x16_f16(bl1, ah0, acc[1][0], 0, 0, 0);
        acc[1][1] = __builtin_amdgcn_mfma_f32_32x32x16_f16(bl1, ah1, acc[1][1], 0, 0, 0);
        acc[0][0] = __builtin_amdgcn_mfma_f32_32x32x16_f16(bh0, al0, acc[0][0], 0, 0, 0);
        acc[0][1] = __builtin_amdgcn_mfma_f32_32x32x16_f16(bh0, al1, acc[0][1], 0, 0, 0);
        acc[1][0] = __builtin_amdgcn_mfma_f32_32x32x16_f16(bh1, al0, acc[1][0], 0, 0, 0);
        acc[1][1] = __builtin_amdgcn_mfma_f32_32x32x16_f16(bh1, al1, acc[1][1], 0, 0, 0);
        __builtin_amdgcn_s_setprio(0);
        // counted wait: keep this iteration's 3 DMAs in flight; drain the 3 that
        // feed kk+1. Last two iterations have no new stage -> drain fully once.
        if (kk < 30) { asm volatile("s_waitcnt vmcnt(3)" ::: "memory"); }
        else         { asm volatile("s_waitcnt vmcnt(0)" ::: "memory"); }
        __builtin_amdgcn_s_barrier();
        asm volatile("" ::: "memory");
        b = (b == 2) ? 0 : b + 1;
    }

    // ---- epilogue: rows in lanes. row(ai) = wr + ai*32 + mrow ----
    float sqr[2]; int labr[2];
    #pragma unroll
    for (int ai = 0; ai < 2; ++ai) {
        sqr[ai]  = sq_r[wr + ai * 32 + mrow];
        labr[ai] = lab_r[wr + ai * 32 + mrow];
    }

    // ---- phase 1: hp / hn_fall ----
    #pragma unroll
    for (int ai = 0; ai < 2; ++ai) {
        float vp = 0.f, vn = 0.f;
        #pragma unroll
        for (int bj = 0; bj < 2; ++bj) {
            #pragma unroll
            for (int r = 0; r < 16; ++r) {
                const int c = wc + bj * 32 + (r & 3) + 8 * (r >> 2) + 4 * half_id;
                float d = sqrtf(fmaxf(sqr[ai] + sq_c[c] - 2.0f * acc[bj][ai][r], 1e-12f));
                const bool pos = (labr[ai] == lab_c[c]);
                vp = fmaxf(vp, pos ? d : 0.f);
                vn = fmaxf(vn, pos ? 0.f : d);
            }
        }
        vp = fmaxf(vp, __shfl_xor(vp, 32, 64));   // merge col halves
        vn = fmaxf(vn, __shfl_xor(vn, 32, 64));
        if (half_id == 0) {
            atomicMax(&hp[rowBase + wr + ai * 32 + mrow],      __float_as_uint(vp));
            atomicMax(&hn_fall[rowBase + wr + ai * 32 + mrow], __float_as_uint(vn));
        }
    }

    // ---- per-row-panel barrier: the 32 blocks sharing py (all blocks co-resident) ----
    __syncthreads();
    unsigned int* ctr = &bars[py * 32];
    if (tid == 0) {
        __threadfence();
        atomicAdd(ctr, 1u);
        while (__hip_atomic_load(ctr, __ATOMIC_ACQUIRE, __HIP_MEMORY_SCOPE_AGENT)
               < nrowblocks)
            __builtin_amdgcn_s_sleep(32);
    }
    __syncthreads();
    if (tid < 256)
        hp_r[tid] = __uint_as_float(__hip_atomic_load(&hp[rowBase + tid],
                                    __ATOMIC_RELAXED, __HIP_MEMORY_SCOPE_AGENT));
    __syncthreads();

    // ---- phase 2: hn_semi = min{d : neg, d > hp} ----
    #pragma unroll
    for (int ai = 0; ai < 2; ++ai) {
        const float hpv = hp_r[wr + ai * 32 + mrow];
        float vm = __builtin_inff();
        #pragma unroll
        for (int bj = 0; bj < 2; ++bj) {
            #pragma unroll
            for (int r = 0; r < 16; ++r) {
                const int c = wc + bj * 32 + (r & 3) + 8 * (r >> 2) + 4 * half_id;
                float d = sqrtf(fmaxf(sqr[ai] + sq_c[c] - 2.0f * acc[bj][ai][r], 1e-12f));
                const bool cand = (labr[ai] != lab_c[c]) && (d > hpv);
                vm = fminf(vm, cand ? d : __builtin_inff());
            }
        }
        vm = fminf(vm, __shfl_xor(vm, 32, 64));
        if (half_id == 0)
            atomicMin(&hn_semi[rowBase + wr + ai * 32 + mrow], __float_as_uint(vm));
    }

    // ---- last-block final reduction ----
    __syncthreads();
    if (tid == 0) {
        __threadfence();
        unsigned int old = atomicAdd(&bars[992], 1u);
        lastflag = (old == nblocks - 1) ? 1 : 0;
    }
    __syncthreads();
    if (!lastflag) return;
    if (tid == 0) __threadfence();      // acquire before cross-XCD reads
    __syncthreads();

    float* FS = (float*)&S[0][0];       // 512 sums
    int*   IC = (int*)(FS + 512);       // 512 counts
    int*   IA = IC + 512;               // 512 any-flags
    int any = 0;
    for (int r = tid; r < N; r += 512) {
        float h  = __uint_as_float(__hip_atomic_load(&hp[r],      __ATOMIC_RELAXED, __HIP_MEMORY_SCOPE_AGENT));
        float hs = __uint_as_float(__hip_atomic_load(&hn_semi[r], __ATOMIC_RELAXED, __HIP_MEMORY_SCOPE_AGENT));
        any |= (hs < h + MARGIN) ? 1 : 0;
    }
    IA[tid] = any;
    __syncthreads();
    for (int s = 256; s; s >>= 1) {
        if (tid < s) IA[tid] |= IA[tid + s];
        __syncthreads();
    }
    const bool has_semi = IA[0] != 0;
    float sum = 0.f; int valid = 0;
    for (int r = tid; r < N; r += 512) {
        float h  = __uint_as_float(__hip_atomic_load(&hp[r], __ATOMIC_RELAXED, __HIP_MEMORY_SCOPE_AGENT));
        float hn = has_semi
            ? __uint_as_float(__hip_atomic_load(&hn_semi[r], __ATOMIC_RELAXED, __HIP_MEMORY_SCOPE_AGENT))
            : __uint_as_float(__hip_atomic_load(&hn_fall[r], __ATOMIC_RELAXED, __HIP_MEMORY_SCOPE_AGENT));
        float t = fmaxf(h - hn + MARGIN, 0.f);
        if (!(t > 0.f)) t = 0.f;        // -inf guard (hn=+inf rows)
        sum += t;
        valid += (t > 0.f) ? 1 : 0;
    }
    FS[tid] = sum; IC[tid] = valid;
    __syncthreads();
    for (int s = 256; s; s >>= 1) {
        if (tid < s) { FS[tid] += FS[tid + s]; IC[tid] += IC[tid + s]; }
        __syncthreads();
    }
    if (tid == 0) {
        float total = FS[0]; int v = IC[0];
        out[0] = (v > 0) ? (total / (float)v) : (total / (float)N);
    }
}

extern "C" void kernel_launch(void* const* d_in, const int* in_sizes, int n_in,
                              void* d_out, int out_size, void* d_ws, size_t ws_size,
                              hipStream_t stream) {
    const float* e      = (const float*)d_in[0];
    const int*   labels = (const int*)d_in[1];
    const int N = in_sizes[1];
    const int D = in_sizes[0] / N;
    float* out = (float*)d_out;

    float*        sq      = (float*)d_ws;
    unsigned int* hp      = (unsigned int*)d_ws + N;
    unsigned int* hn_fall = hp + N;
    unsigned int* hn_semi = hn_fall + N;
    unsigned int* bars    = hn_semi + N;     // 32 counters (128B-spaced) + done @992

    const size_t small_bytes = ((size_t)(4 * N + 1024) * 4 + 255) & ~(size_t)255;
    _Float16* pan = (_Float16*)((char*)d_ws + small_bytes);

    prep_kernel<<<N / 8, 256, 0, stream>>>(e, pan, sq, hp, hn_fall, hn_semi, bars, N, D);

    const int ntx = N / 128, nty = N / 256;  // 32 x 16 tiles = 512 blocks = 2/CU
    fused_kernel<<<ntx * nty, 512, 0, stream>>>(pan, labels, sq, hp, hn_fall, hn_semi,
                                                bars, out, N, D,
                                                (unsigned)ntx, (unsigned)(ntx * nty));
}

// Round 3
// 140.077 us; speedup vs baseline: 1.0659x; 1.0659x over previous
//
#include <hip/hip_runtime.h>
#include <math.h>

// OnlineTripletLoss on MI355X — Round 13.
// R12 post-mortem: counted-vmcnt on the 2-phase loop REGRESSED (85 -> 96 us) — the
//   documented null quadrant (m218/m233): the 2-phase stall is structural
//   (stage+barrier lockstep), not the DMA drain (DMAs age ~5000 cyc >> 900 latency).
// R13: real 8-phase-style port (T3+T4+T5 in the proven combination):
//   256x256 tile, 8 waves (wave tile 128x64 -> 2.0 MFMA per ds_read_b128 vs 1.5),
//   BK=32 dbuf (2x64 KB LDS), 4 sub-phases per K-tile:
//     {6 ds_reads | 2 DMA issues -> s_barrier -> setprio(1) MFMA cluster setprio(0)
//      -> s_barrier}, vmcnt(0) only once per K-tile (4 phases).
//   Grid 256 = 1 block/CU exactly co-resident (needed for spin barriers).
// ws: sq[N] | hp[N] | hn_fall[N] | hn_semi[N] | bars[1024] | pad | pan[N*2D] f16

constexpr float MARGIN = 0.3f;

typedef _Float16 half8    __attribute__((ext_vector_type(8)));
typedef float    floatx16 __attribute__((ext_vector_type(16)));

#define GLD_LDS16(gp, lp)                                                              \
    __builtin_amdgcn_global_load_lds(                                                  \
        (const __attribute__((address_space(1))) void*)(gp),                           \
        (__attribute__((address_space(3))) void*)(lp), 16, 0, 0)

// prep: 8 rows/block (512 blocks); builds pan[p][kc][r][8] (kc<64 hi, kc>=64 lo),
// sq, per-row init, bars. (Unchanged from R12 — passed.)
__global__ __launch_bounds__(256)
void prep_kernel(const float* __restrict__ e, _Float16* __restrict__ pan,
                 float* __restrict__ sq, unsigned int* __restrict__ hp,
                 unsigned int* __restrict__ hn_fall, unsigned int* __restrict__ hn_semi,
                 unsigned int* __restrict__ bars, int N, int D) {
    __shared__ float red[256];
    if (blockIdx.x == 0 && threadIdx.x < 32) bars[threadIdx.x * 32] = 0u;
    const int r0  = blockIdx.x * 8;
    const int p   = r0 >> 7;
    const int rl  = r0 & 127;
    const int r   = threadIdx.x & 7;
    const int c8  = threadIdx.x >> 3;
    const int row = r0 + r;
    const float* er = e + (size_t)row * D;
    float s = 0.f;
    #pragma unroll
    for (int it = 0; it < 2; ++it) {
        const int kw = c8 + it * 32;
        const float4 x0 = *(const float4*)&er[kw * 8];
        const float4 x1 = *(const float4*)&er[kw * 8 + 4];
        const float xv[8] = {x0.x, x0.y, x0.z, x0.w, x1.x, x1.y, x1.z, x1.w};
        half8 hi, lo;
        #pragma unroll
        for (int jj = 0; jj < 8; ++jj) {
            _Float16 h = (_Float16)xv[jj];
            hi[jj] = h;
            lo[jj] = (_Float16)(xv[jj] - (float)h);
            s += xv[jj] * xv[jj];
        }
        *(half8*)&pan[((size_t)(p * 128 + kw) * 128 + rl + r) * 8]      = hi;
        *(half8*)&pan[((size_t)(p * 128 + 64 + kw) * 128 + rl + r) * 8] = lo;
    }
    red[threadIdx.x] = s;
    __syncthreads();
    if (threadIdx.x < 8) {
        float t = 0.f;
        #pragma unroll
        for (int c = 0; c < 32; ++c) t += red[threadIdx.x + 8 * c];
        const int rw = r0 + threadIdx.x;
        sq[rw]      = t;
        hp[rw]      = 0u;
        hn_fall[rw] = 0u;
        hn_semi[rw] = 0x7f800000u;
    }
}

// Fused: tile 256x256, 512 thr = 8 waves (2 row x 4 col) of 128x64.
// Buffer (32768 halves = 64 KB): A[kcl 0..7][256][8] | B[kcl 0..7][256][8] @16384.
// kcl 0..3 = hi k-chunks (4t..4t+3), 4..7 = lo. Double-buffered (t parity).
__global__ __launch_bounds__(512, 2)
void fused_kernel(const _Float16* __restrict__ pan, const int* __restrict__ labels,
                  const float* __restrict__ sq,
                  unsigned int* __restrict__ hp,
                  unsigned int* __restrict__ hn_fall,
                  unsigned int* __restrict__ hn_semi,
                  unsigned int* __restrict__ bars,
                  float* __restrict__ out,
                  int N, int D, unsigned int nrowblocks, unsigned int nblocks) {
    __shared__ __attribute__((aligned(16))) _Float16 S[2][32768];   // 128 KB
    __shared__ float sq_r[256], sq_c[256], hp_r[256];
    __shared__ int   lab_r[256], lab_c[256];
    __shared__ int   lastflag;

    const int tid  = threadIdx.x;
    const int lane = tid & 63;
    const int wave = tid >> 6;             // 0..7
    const int wr   = (wave >> 2) * 128;    // 0,128
    const int wcol = (wave & 3) * 64;      // 0,64,128,192
    const int mrow = lane & 31;
    const int half_id = lane >> 5;

    // XCD swizzle: each of 8 XCDs gets a 4(px) x 8(py) region of the 16x16 grid
    const int j  = blockIdx.x & 7;
    const int i  = blockIdx.x >> 3;        // 0..31
    const int px = (j & 3) * 4 + (i & 3);          // 0..15 (256-col tiles)
    const int py = (j >> 2) * 8 + (i >> 2);        // 0..15 (256-row tiles)
    const int rowBase = py * 256;
    const int colBase = px * 256;

    if (tid < 256) {
        sq_r[tid]  = sq[rowBase + tid];
        lab_r[tid] = labels[rowBase + tid];
    } else {
        const int t2 = tid - 256;
        sq_c[t2]  = sq[colBase + t2];
        lab_c[t2] = labels[colBase + t2];
    }

    floatx16 acc[2][4];   // acc[bj][ai]: cols in regs (bj), rows in lanes (ai)
    #pragma unroll
    for (int b = 0; b < 2; ++b)
        #pragma unroll
        for (int a = 0; a < 4; ++a)
            #pragma unroll
            for (int r = 0; r < 16; ++r) acc[b][a][r] = 0.f;

    // 64 slabs of 1 KB per K-tile: A = 8 kcl x 4 row-quarters, B same @ +16384.
    // wave w owns slabs 8w..8w+7 (2 per phase).
    auto stage_slab = [&](int nxt, int t, int u) {
        const int s = wave * 8 + u;
        int kcl, pp, rowin, lofs;
        if (s < 32) {                      // A slab
            kcl = s >> 2; const int rq = s & 3;
            pp    = 2 * py + (rq >> 1);
            rowin = (rq & 1) * 64 + lane;
            lofs  = (kcl * 256 + rq * 64) * 8;
        } else {                           // B slab
            const int u2 = s - 32;
            kcl = u2 >> 2; const int cq = u2 & 3;
            pp    = 2 * px + (cq >> 1);
            rowin = (cq & 1) * 64 + lane;
            lofs  = 16384 + (kcl * 256 + cq * 64) * 8;
        }
        const int kc = (kcl < 4) ? (4 * t + kcl) : (64 + 4 * t + (kcl - 4));
        const _Float16* g = pan + ((size_t)(pp * 128 + kc) * 128 + rowin) * 8;
        GLD_LDS16(g, &S[nxt][lofs]);
    };

    // prologue: stage K-tile 0, full drain once.
    #pragma unroll
    for (int u = 0; u < 8; ++u) stage_slab(0, 0, u);
    __syncthreads();

    #pragma unroll 1
    for (int t = 0; t < 16; ++t) {
        const int cur = t & 1, nxt = cur ^ 1;
        const _Float16* Sc = &S[cur][0];
        half8 ah[4], bh[2];
        #pragma unroll
        for (int ph = 0; ph < 4; ++ph) {
            // ph 0: hi pair0 (kcl 0,1) | ph 1: lo pair0 (4,5) | ph 2: hi pair1 (2,3)
            // ph 3: lo pair1 (6,7)
            const int kbase = (ph >> 1) * 2 + (ph & 1) * 4;
            half8 av[4], bv[2];
            #pragma unroll
            for (int ai = 0; ai < 4; ++ai)
                av[ai] = *(const half8*)&Sc[((kbase + half_id) * 256 + wr + ai * 32 + mrow) * 8];
            #pragma unroll
            for (int bj = 0; bj < 2; ++bj)
                bv[bj] = *(const half8*)&Sc[16384 + ((kbase + half_id) * 256 + wcol + bj * 32 + mrow) * 8];
            if (t + 1 < 16) {              // 2 DMA issues per phase for next tile
                stage_slab(nxt, t + 1, 2 * ph);
                stage_slab(nxt, t + 1, 2 * ph + 1);
            }
            asm volatile("" ::: "memory");
            __builtin_amdgcn_s_barrier();
            asm volatile("" ::: "memory");
            __builtin_amdgcn_s_setprio(1);
            if ((ph & 1) == 0) {           // hi.hi pass (8 MFMA); keep frags for lo phase
                #pragma unroll
                for (int bj = 0; bj < 2; ++bj)
                    #pragma unroll
                    for (int ai = 0; ai < 4; ++ai)
                        acc[bj][ai] = __builtin_amdgcn_mfma_f32_32x32x16_f16(
                            bv[bj], av[ai], acc[bj][ai], 0, 0, 0);
                #pragma unroll
                for (int ai = 0; ai < 4; ++ai) ah[ai] = av[ai];
                bh[0] = bv[0]; bh[1] = bv[1];
            } else {                       // lo.hi + hi.lo passes (16 MFMA)
                #pragma unroll
                for (int bj = 0; bj < 2; ++bj)
                    #pragma unroll
                    for (int ai = 0; ai < 4; ++ai)
                        acc[bj][ai] = __builtin_amdgcn_mfma_f32_32x32x16_f16(
                            bh[bj], av[ai], acc[bj][ai], 0, 0, 0);
                #pragma unroll
                for (int bj = 0; bj < 2; ++bj)
                    #pragma unroll
                    for (int ai = 0; ai < 4; ++ai)
                        acc[bj][ai] = __builtin_amdgcn_mfma_f32_32x32x16_f16(
                            bv[bj], ah[ai], acc[bj][ai], 0, 0, 0);
            }
            __builtin_amdgcn_s_setprio(0);
            if (ph == 3) { asm volatile("s_waitcnt vmcnt(0)" ::: "memory"); }
            asm volatile("" ::: "memory");
            __builtin_amdgcn_s_barrier();
            asm volatile("" ::: "memory");
        }
    }

    // ---- epilogue: rows in lanes. row(ai) = wr + ai*32 + mrow ----
    float sqr[4]; int labr[4];
    #pragma unroll
    for (int ai = 0; ai < 4; ++ai) {
        sqr[ai]  = sq_r[wr + ai * 32 + mrow];
        labr[ai] = lab_r[wr + ai * 32 + mrow];
    }

    // ---- phase 1: hp / hn_fall ----
    #pragma unroll
    for (int ai = 0; ai < 4; ++ai) {
        float vp = 0.f, vn = 0.f;
        #pragma unroll
        for (int bj = 0; bj < 2; ++bj) {
            #pragma unroll
            for (int r = 0; r < 16; ++r) {
                const int c = wcol + bj * 32 + (r & 3) + 8 * (r >> 2) + 4 * half_id;
                float d = sqrtf(fmaxf(sqr[ai] + sq_c[c] - 2.0f * acc[bj][ai][r], 1e-12f));
                const bool pos = (labr[ai] == lab_c[c]);
                vp = fmaxf(vp, pos ? d : 0.f);
                vn = fmaxf(vn, pos ? 0.f : d);
            }
        }
        vp = fmaxf(vp, __shfl_xor(vp, 32, 64));   // merge col halves
        vn = fmaxf(vn, __shfl_xor(vn, 32, 64));
        if (half_id == 0) {
            atomicMax(&hp[rowBase + wr + ai * 32 + mrow],      __float_as_uint(vp));
            atomicMax(&hn_fall[rowBase + wr + ai * 32 + mrow], __float_as_uint(vn));
        }
    }

    // ---- per-row-panel barrier: 16 col-blocks share each py; all co-resident ----
    __syncthreads();
    unsigned int* ctr = &bars[py * 32];
    if (tid == 0) {
        __threadfence();
        atomicAdd(ctr, 1u);
        while (__hip_atomic_load(ctr, __ATOMIC_ACQUIRE, __HIP_MEMORY_SCOPE_AGENT)
               < nrowblocks)
            __builtin_amdgcn_s_sleep(32);
    }
    __syncthreads();
    if (tid < 256)
        hp_r[tid] = __uint_as_float(__hip_atomic_load(&hp[rowBase + tid],
                                    __ATOMIC_RELAXED, __HIP_MEMORY_SCOPE_AGENT));
    __syncthreads();

    // ---- phase 2: hn_semi = min{d : neg, d > hp} ----
    #pragma unroll
    for (int ai = 0; ai < 4; ++ai) {
        const float hpv = hp_r[wr + ai * 32 + mrow];
        float vm = __builtin_inff();
        #pragma unroll
        for (int bj = 0; bj < 2; ++bj) {
            #pragma unroll
            for (int r = 0; r < 16; ++r) {
                const int c = wcol + bj * 32 + (r & 3) + 8 * (r >> 2) + 4 * half_id;
                float d = sqrtf(fmaxf(sqr[ai] + sq_c[c] - 2.0f * acc[bj][ai][r], 1e-12f));
                const bool cand = (labr[ai] != lab_c[c]) && (d > hpv);
                vm = fminf(vm, cand ? d : __builtin_inff());
            }
        }
        vm = fminf(vm, __shfl_xor(vm, 32, 64));
        if (half_id == 0)
            atomicMin(&hn_semi[rowBase + wr + ai * 32 + mrow], __float_as_uint(vm));
    }

    // ---- last-block final reduction ----
    __syncthreads();
    if (tid == 0) {
        __threadfence();
        unsigned int old = atomicAdd(&bars[992], 1u);
        lastflag = (old == nblocks - 1) ? 1 : 0;
    }
    __syncthreads();
    if (!lastflag) return;
    if (tid == 0) __threadfence();      // acquire before cross-XCD reads
    __syncthreads();

    float* FS = (float*)&S[0][0];       // 512 sums
    int*   IC = (int*)(FS + 512);       // 512 counts
    int*   IA = IC + 512;               // 512 any-flags
    int any = 0;
    for (int r = tid; r < N; r += 512) {
        float h  = __uint_as_float(__hip_atomic_load(&hp[r],      __ATOMIC_RELAXED, __HIP_MEMORY_SCOPE_AGENT));
        float hs = __uint_as_float(__hip_atomic_load(&hn_semi[r], __ATOMIC_RELAXED, __HIP_MEMORY_SCOPE_AGENT));
        any |= (hs < h + MARGIN) ? 1 : 0;
    }
    IA[tid] = any;
    __syncthreads();
    for (int s = 256; s; s >>= 1) {
        if (tid < s) IA[tid] |= IA[tid + s];
        __syncthreads();
    }
    const bool has_semi = IA[0] != 0;
    float sum = 0.f; int valid = 0;
    for (int r = tid; r < N; r += 512) {
        float h  = __uint_as_float(__hip_atomic_load(&hp[r], __ATOMIC_RELAXED, __HIP_MEMORY_SCOPE_AGENT));
        float hn = has_semi
            ? __uint_as_float(__hip_atomic_load(&hn_semi[r], __ATOMIC_RELAXED, __HIP_MEMORY_SCOPE_AGENT))
            : __uint_as_float(__hip_atomic_load(&hn_fall[r], __ATOMIC_RELAXED, __HIP_MEMORY_SCOPE_AGENT));
        float t = fmaxf(h - hn + MARGIN, 0.f);
        if (!(t > 0.f)) t = 0.f;        // -inf guard (hn=+inf rows)
        sum += t;
        valid += (t > 0.f) ? 1 : 0;
    }
    FS[tid] = sum; IC[tid] = valid;
    __syncthreads();
    for (int s = 256; s; s >>= 1) {
        if (tid < s) { FS[tid] += FS[tid + s]; IC[tid] += IC[tid + s]; }
        __syncthreads();
    }
    if (tid == 0) {
        float total = FS[0]; int v = IC[0];
        out[0] = (v > 0) ? (total / (float)v) : (total / (float)N);
    }
}

extern "C" void kernel_launch(void* const* d_in, const int* in_sizes, int n_in,
                              void* d_out, int out_size, void* d_ws, size_t ws_size,
                              hipStream_t stream) {
    const float* e      = (const float*)d_in[0];
    const int*   labels = (const int*)d_in[1];
    const int N = in_sizes[1];
    const int D = in_sizes[0] / N;
    float* out = (float*)d_out;

    float*        sq      = (float*)d_ws;
    unsigned int* hp      = (unsigned int*)d_ws + N;
    unsigned int* hn_fall = hp + N;
    unsigned int* hn_semi = hn_fall + N;
    unsigned int* bars    = hn_semi + N;     // 32 counters (128B-spaced) + done @992

    const size_t small_bytes = ((size_t)(4 * N + 1024) * 4 + 255) & ~(size_t)255;
    _Float16* pan = (_Float16*)((char*)d_ws + small_bytes);

    prep_kernel<<<N / 8, 256, 0, stream>>>(e, pan, sq, hp, hn_fall, hn_semi, bars, N, D);

    const int ntx = N / 256, nty = N / 256;  // 16 x 16 tiles = 256 blocks = 1/CU
    fused_kernel<<<ntx * nty, 512, 0, stream>>>(pan, labels, sq, hp, hn_fall, hn_semi,
                                                bars, out, N, D,
                                                (unsigned)ntx, (unsigned)(ntx * nty));
}